// Round 1
// baseline (3991.505 us; speedup 1.0000x reference)
//
#include <hip/hip_runtime.h>
#include <math.h>

#define B_      2
#define S_      2048
#define HIDDEN_ 2048
#define HEADS_  16
#define QLORA_  1024
#define KVLORA_ 512
#define NOPE_   128
#define ROPE_   64
#define QHEAD_  192   // NOPE + ROPE
#define VHEAD_  128

// ---------------------------------------------------------------------------
// Generic fp32 tiled GEMM: C[M,N] = A[M,K] @ B[K,N]
// Tile 64x64, BK=16, block 16x16, each thread 4x4.
// Grid encodes M,N (all our shapes divide evenly: M%64==0, N%64==0, K%16==0).
// ---------------------------------------------------------------------------
__global__ __launch_bounds__(256) void gemm_f32(
    const float* __restrict__ A, int lda,
    const float* __restrict__ B, int ldb,
    float* __restrict__ C, int ldc,
    int K) {
  __shared__ __align__(16) float As[16][68];  // [k][m], pad 4 -> fp4-aligned rows
  __shared__ __align__(16) float Bs[16][68];  // [k][n]
  const int tx = threadIdx.x, ty = threadIdx.y;
  const int tid = ty * 16 + tx;
  const int bm = blockIdx.y * 64, bn = blockIdx.x * 64;
  const int am = tid >> 2, ak = (tid & 3) << 2;    // A: row am, k-chunk ak
  const int bk = tid >> 4, bn0 = (tid & 15) << 2;  // B: row bk, n-chunk bn0

  float acc[4][4] = {};

  for (int k0 = 0; k0 < K; k0 += 16) {
    float4 av = *(const float4*)(A + (size_t)(bm + am) * lda + k0 + ak);
    float4 bv = *(const float4*)(B + (size_t)(k0 + bk) * ldb + bn + bn0);
    __syncthreads();  // protect LDS from previous iteration's readers
    As[ak + 0][am] = av.x;
    As[ak + 1][am] = av.y;
    As[ak + 2][am] = av.z;
    As[ak + 3][am] = av.w;
    *(float4*)&Bs[bk][bn0] = bv;
    __syncthreads();
#pragma unroll
    for (int k = 0; k < 16; ++k) {
      float4 a = *(const float4*)&As[k][ty << 2];  // broadcast across 16 tx lanes
      float4 b = *(const float4*)&Bs[k][tx << 2];  // 16 distinct float4 = 2-way (free)
      float aa[4] = {a.x, a.y, a.z, a.w};
      float bb[4] = {b.x, b.y, b.z, b.w};
#pragma unroll
      for (int i = 0; i < 4; ++i)
#pragma unroll
        for (int j = 0; j < 4; ++j) acc[i][j] = fmaf(aa[i], bb[j], acc[i][j]);
    }
  }

#pragma unroll
  for (int i = 0; i < 4; ++i) {
    float4 v = make_float4(acc[i][0], acc[i][1], acc[i][2], acc[i][3]);
    *(float4*)(C + (size_t)(bm + ty * 4 + i) * ldc + bn + tx * 4) = v;
  }
}

// ---------------------------------------------------------------------------
// RoPE (in-place): q rope part (per b,s,h -> q[..., 128:192]) and
// shared k_rope (ckv[..., 512:576]). h' in [0,16]: h'<16 -> q head, 16 -> k.
// Uses accurate sinf/cosf: ref computes angles in fp32 too (ang up to ~2047).
// ---------------------------------------------------------------------------
__global__ void rope_kernel(float* __restrict__ q, float* __restrict__ ckv,
                            const int* __restrict__ position) {
  int idx = blockIdx.x * blockDim.x + threadIdx.x;
  const int total = B_ * S_ * 17 * 32;
  if (idx >= total) return;
  int i = idx & 31;        // freq index 0..31
  int u = idx >> 5;
  int h = u % 17;
  int bs = u / 17;         // 0..B*S-1
  int s = bs % S_;
  float pos = (float)position[s];
  float inv_freq = powf(10000.0f, -(float)i / 32.0f);  // theta^(-2i/ROPE)
  float ang = pos * inv_freq;
  float c = cosf(ang), sn = sinf(ang);
  float* t = (h < 16) ? (q + (size_t)bs * (HEADS_ * QHEAD_) + h * QHEAD_ + NOPE_)
                      : (ckv + (size_t)bs * (KVLORA_ + ROPE_) + KVLORA_);
  float t1 = t[i], t2 = t[i + 32];
  t[i]      = t1 * c - t2 * sn;
  t[i + 32] = t2 * c + t1 * sn;
}

// ---------------------------------------------------------------------------
// Flash-style attention, fp32. Block = 256 threads, 32 queries/block,
// key tiles of 32, online softmax. Grid: (S/32, HEADS, B).
// Thread t: row r = t/8 (0..31); col group cg = t%8.
//   scores: computes S[r][4cg..4cg+3]
//   PV:     owns O[r][4cg + 32m + j], m,j in 0..3  (conflict-free Vs reads)
// ---------------------------------------------------------------------------
__global__ __launch_bounds__(256) void attn_kernel(
    const float* __restrict__ q,    // [B*S, HEADS*192] (rope applied)
    const float* __restrict__ kv,   // [B*S, HEADS*256] (k_nope | v per head)
    const float* __restrict__ ckv,  // [B*S, 576] cols 512.. = roped k_rope
    float* __restrict__ out) {      // [B*S, HEADS*128]
  const int qt = blockIdx.x, h = blockIdx.y, b = blockIdx.z;
  __shared__ __align__(16) float Qs[32][196];   // [r][d]
  __shared__ __align__(16) float Ks[192][36];   // [d][c] transposed
  __shared__ __align__(16) float Vs[32][132];   // [c][d]
  __shared__ __align__(16) float Ps[32][36];    // [r][c]

  const int tid = threadIdx.x;
  const int r = tid >> 3;   // 0..31
  const int cg = tid & 7;   // 0..7

  const float* qbase = q + ((size_t)(b * S_ + qt * 32)) * (HEADS_ * QHEAD_) + h * QHEAD_;
  for (int idx = tid; idx < 32 * 192; idx += 256) {
    int rr = idx / 192, dd = idx % 192;
    Qs[rr][dd] = qbase[(size_t)rr * (HEADS_ * QHEAD_) + dd];
  }

  const float* kn_base = kv + ((size_t)(b * S_)) * (HEADS_ * 256) + h * 256;
  const float* kr_base = ckv + ((size_t)(b * S_)) * (KVLORA_ + ROPE_) + KVLORA_;
  const float* v_base  = kn_base + 128;

  float m_run = -1e30f, l_run = 0.0f;
  float o[4][4] = {};
  const float scale = 0.072168783649f;  // 1/sqrt(192)

  for (int kt = 0; kt < S_; kt += 32) {
    __syncthreads();  // previous tile's LDS readers done
    for (int idx = tid; idx < 32 * 192; idx += 256) {
      int c = idx / 192, d = idx % 192;
      float val = (d < 128) ? kn_base[(size_t)(kt + c) * (HEADS_ * 256) + d]
                            : kr_base[(size_t)(kt + c) * (KVLORA_ + ROPE_) + (d - 128)];
      Ks[d][c] = val;
    }
    for (int idx = tid; idx < 32 * 128; idx += 256) {
      int c = idx / 128, d = idx % 128;
      Vs[c][d] = v_base[(size_t)(kt + c) * (HEADS_ * 256) + d];
    }
    __syncthreads();

    // ---- scores: S[r][4cg+j] = sum_d Qs[r][d] * Ks[d][4cg+j]
    float sc[4] = {0.f, 0.f, 0.f, 0.f};
#pragma unroll 8
    for (int d = 0; d < 192; ++d) {
      float qv = Qs[r][d];
      float4 kk = *(const float4*)&Ks[d][cg << 2];
      sc[0] = fmaf(qv, kk.x, sc[0]);
      sc[1] = fmaf(qv, kk.y, sc[1]);
      sc[2] = fmaf(qv, kk.z, sc[2]);
      sc[3] = fmaf(qv, kk.w, sc[3]);
    }
#pragma unroll
    for (int j = 0; j < 4; ++j) sc[j] *= scale;

    // ---- online softmax across the 8 lanes sharing row r (contiguous lanes)
    float mt = fmaxf(fmaxf(sc[0], sc[1]), fmaxf(sc[2], sc[3]));
    mt = fmaxf(mt, __shfl_xor(mt, 1));
    mt = fmaxf(mt, __shfl_xor(mt, 2));
    mt = fmaxf(mt, __shfl_xor(mt, 4));
    float m_new = fmaxf(m_run, mt);
    float p[4], ls = 0.f;
#pragma unroll
    for (int j = 0; j < 4; ++j) { p[j] = __expf(sc[j] - m_new); ls += p[j]; }
    ls += __shfl_xor(ls, 1);
    ls += __shfl_xor(ls, 2);
    ls += __shfl_xor(ls, 4);
    float alpha = __expf(m_run - m_new);  // first tile: exp(-huge)=0
    l_run = l_run * alpha + ls;
    m_run = m_new;
#pragma unroll
    for (int m = 0; m < 4; ++m)
#pragma unroll
      for (int j = 0; j < 4; ++j) o[m][j] *= alpha;

    *(float4*)&Ps[r][cg << 2] = make_float4(p[0], p[1], p[2], p[3]);
    __syncthreads();  // make Ps visible (and cheap ordering guarantee)

    // ---- PV: O[r][4cg+32m+j] += sum_k Ps[r][k] * Vs[k][4cg+32m+j]
#pragma unroll 4
    for (int k = 0; k < 32; ++k) {
      float pv = Ps[r][k];
#pragma unroll
      for (int m = 0; m < 4; ++m) {
        float4 vv = *(const float4*)&Vs[k][(cg << 2) + 32 * m];
        o[m][0] = fmaf(pv, vv.x, o[m][0]);
        o[m][1] = fmaf(pv, vv.y, o[m][1]);
        o[m][2] = fmaf(pv, vv.z, o[m][2]);
        o[m][3] = fmaf(pv, vv.w, o[m][3]);
      }
    }
  }

  float inv_l = 1.0f / l_run;
  float* obase = out + ((size_t)(b * S_ + qt * 32 + r)) * (HEADS_ * VHEAD_) + h * VHEAD_;
#pragma unroll
  for (int m = 0; m < 4; ++m) {
#pragma unroll
    for (int j = 0; j < 4; ++j) obase[(cg << 2) + 32 * m + j] = o[m][j] * inv_l;
  }
}

// ---------------------------------------------------------------------------
extern "C" void kernel_launch(void* const* d_in, const int* in_sizes, int n_in,
                              void* d_out, int out_size, void* d_ws, size_t ws_size,
                              hipStream_t stream) {
  const float* x        = (const float*)d_in[0];  // [B,S,2048]
  const int*   position = (const int*)d_in[1];    // [S]
  const float* Wq_down  = (const float*)d_in[2];  // [2048,1024]
  const float* Wq_up    = (const float*)d_in[3];  // [1024,3072]
  const float* Wkv_down = (const float*)d_in[4];  // [2048,576]
  const float* Wkv_up   = (const float*)d_in[5];  // [512,4096]
  const float* Wout     = (const float*)d_in[6];  // [2048,2048]
  float* out = (float*)d_out;                     // [B,S,2048]

  const size_t M = (size_t)B_ * S_;  // 4096
  float* ws    = (float*)d_ws;
  float* qdown = ws;                       // 4096 x 1024
  float* qbuf  = qdown + M * QLORA_;       // 4096 x 3072
  float* ckv   = qbuf + M * HEADS_ * QHEAD_;       // 4096 x 576
  float* kvbuf = ckv + M * (KVLORA_ + ROPE_);      // 4096 x 4096
  float* ao    = kvbuf + M * HEADS_ * (NOPE_ + VHEAD_);  // 4096 x 2048

  dim3 blk(16, 16);

  // qdown = x @ Wq_down        (4096,1024,K=2048)
  gemm_f32<<<dim3(1024 / 64, 4096 / 64), blk, 0, stream>>>(x, HIDDEN_, Wq_down, QLORA_, qdown, QLORA_, HIDDEN_);
  // q = qdown @ Wq_up          (4096,3072,K=1024)
  gemm_f32<<<dim3(3072 / 64, 4096 / 64), blk, 0, stream>>>(qdown, QLORA_, Wq_up, 3072, qbuf, 3072, QLORA_);
  // ckv = x @ Wkv_down         (4096,576,K=2048)
  gemm_f32<<<dim3(576 / 64, 4096 / 64), blk, 0, stream>>>(x, HIDDEN_, Wkv_down, 576, ckv, 576, HIDDEN_);
  // rope in-place on q (per head) and ckv[:,512:576]
  {
    int total = B_ * S_ * 17 * 32;
    rope_kernel<<<(total + 255) / 256, 256, 0, stream>>>(qbuf, ckv, position);
  }
  // kv = ckv[:, :512] @ Wkv_up (4096,4096,K=512)  (lda=576 skips rope cols)
  gemm_f32<<<dim3(4096 / 64, 4096 / 64), blk, 0, stream>>>(ckv, 576, Wkv_up, 4096, kvbuf, 4096, KVLORA_);
  // attention -> ao [4096, 2048]
  attn_kernel<<<dim3(S_ / 32, HEADS_, B_), 256, 0, stream>>>(qbuf, kvbuf, ckv, ao);
  // out = ao @ Wout            (4096,2048,K=2048)
  gemm_f32<<<dim3(2048 / 64, 4096 / 64), blk, 0, stream>>>(ao, HIDDEN_, Wout, HIDDEN_, out, HIDDEN_, HIDDEN_);
}

// Round 2
// 1758.800 us; speedup vs baseline: 2.2694x; 2.2694x over previous
//
#include <hip/hip_runtime.h>
#include <math.h>

#define B_      2
#define S_      2048
#define HIDDEN_ 2048
#define HEADS_  16
#define QLORA_  1024
#define KVLORA_ 512
#define NOPE_   128
#define ROPE_   64
#define QHEAD_  192
#define VHEAD_  128

typedef __attribute__((ext_vector_type(8))) short bf16x8;
typedef __attribute__((ext_vector_type(4))) float f32x4;

static __device__ __forceinline__ unsigned short f2bf(float f) {
  unsigned u = __builtin_bit_cast(unsigned, f);
  u += 0x7fffu + ((u >> 16) & 1u);  // RTNE
  return (unsigned short)(u >> 16);
}
static __device__ __forceinline__ float b2f(unsigned short s) {
  unsigned u = ((unsigned)s) << 16;
  return __builtin_bit_cast(float, u);
}

// ---------------------------------------------------------------------------
// fp32 tiled GEMM: C[M,N] = A[M,K] @ B[K,N]; C stored as float or bf16(ushort).
// Tile 64x64, BK=16, block 16x16, 4x4 per thread.
// ---------------------------------------------------------------------------
template <typename TC>
__global__ __launch_bounds__(256) void gemm_f32_t(
    const float* __restrict__ A, int lda,
    const float* __restrict__ B, int ldb,
    TC* __restrict__ C, int ldc, int K) {
  __shared__ __align__(16) float As[16][68];
  __shared__ __align__(16) float Bs[16][68];
  const int tx = threadIdx.x, ty = threadIdx.y;
  const int tid = ty * 16 + tx;
  const int bm = blockIdx.y * 64, bn = blockIdx.x * 64;
  const int am = tid >> 2, ak = (tid & 3) << 2;
  const int bk = tid >> 4, bn0 = (tid & 15) << 2;

  float acc[4][4] = {};

  for (int k0 = 0; k0 < K; k0 += 16) {
    float4 av = *(const float4*)(A + (size_t)(bm + am) * lda + k0 + ak);
    float4 bv = *(const float4*)(B + (size_t)(k0 + bk) * ldb + bn + bn0);
    __syncthreads();
    As[ak + 0][am] = av.x;
    As[ak + 1][am] = av.y;
    As[ak + 2][am] = av.z;
    As[ak + 3][am] = av.w;
    *(float4*)&Bs[bk][bn0] = bv;
    __syncthreads();
#pragma unroll
    for (int k = 0; k < 16; ++k) {
      float4 a = *(const float4*)&As[k][ty << 2];
      float4 b = *(const float4*)&Bs[k][tx << 2];
      float aa[4] = {a.x, a.y, a.z, a.w};
      float bb[4] = {b.x, b.y, b.z, b.w};
#pragma unroll
      for (int i = 0; i < 4; ++i)
#pragma unroll
        for (int j = 0; j < 4; ++j) acc[i][j] = fmaf(aa[i], bb[j], acc[i][j]);
    }
  }

#pragma unroll
  for (int i = 0; i < 4; ++i) {
    if constexpr (sizeof(TC) == 4) {
      float4 v = make_float4(acc[i][0], acc[i][1], acc[i][2], acc[i][3]);
      *(float4*)((float*)C + (size_t)(bm + ty * 4 + i) * ldc + bn + tx * 4) = v;
    } else {
      ushort4 v;
      v.x = f2bf(acc[i][0]); v.y = f2bf(acc[i][1]);
      v.z = f2bf(acc[i][2]); v.w = f2bf(acc[i][3]);
      *(ushort4*)((unsigned short*)C + (size_t)(bm + ty * 4 + i) * ldc + bn + tx * 4) = v;
    }
  }
}

// ---------------------------------------------------------------------------
// RoPE: q (bf16, in-place on qb[bs][3072], cols h*192+128..191) and k_rope
// (read fp32 ckv[bs][512..575], write bf16 krb[bs][64]).
// ---------------------------------------------------------------------------
__global__ void rope_kernel(unsigned short* __restrict__ qb,
                            const float* __restrict__ ckv,
                            unsigned short* __restrict__ krb,
                            const int* __restrict__ position) {
  int idx = blockIdx.x * blockDim.x + threadIdx.x;
  const int total = B_ * S_ * 17 * 32;
  if (idx >= total) return;
  int i = idx & 31;
  int u = idx >> 5;
  int h = u % 17;
  int bs = u / 17;
  int s = bs % S_;
  float pos = (float)position[s];
  float inv_freq = powf(10000.0f, -(float)i / 32.0f);
  float ang = pos * inv_freq;
  float c = cosf(ang), sn = sinf(ang);
  if (h < 16) {
    unsigned short* t = qb + (size_t)bs * 3072 + h * QHEAD_ + NOPE_;
    float t1 = b2f(t[i]), t2 = b2f(t[i + 32]);
    t[i]      = f2bf(t1 * c - t2 * sn);
    t[i + 32] = f2bf(t2 * c + t1 * sn);
  } else {
    const float* t = ckv + (size_t)bs * (KVLORA_ + ROPE_) + KVLORA_;
    float t1 = t[i], t2 = t[i + 32];
    krb[(size_t)bs * 64 + i]      = f2bf(t1 * c - t2 * sn);
    krb[(size_t)bs * 64 + i + 32] = f2bf(t2 * c + t1 * sn);
  }
}

// ---------------------------------------------------------------------------
// V transpose: kvb bf16 [bs][h*256+128+d] -> vtb bf16 [(b*16+h)*128+d][s]
// ---------------------------------------------------------------------------
__global__ __launch_bounds__(256) void pack_vt(const unsigned short* __restrict__ kvb,
                                               unsigned short* __restrict__ vtb) {
  __shared__ unsigned short tile[32][33];
  int s0 = blockIdx.x * 32, d0 = blockIdx.y * 32, bh = blockIdx.z;
  int b = bh >> 4, h = bh & 15;
  int tx = threadIdx.x, ty = threadIdx.y;  // block (32,8)
#pragma unroll
  for (int i = 0; i < 4; ++i) {
    int sy = ty + i * 8;
    tile[sy][tx] = kvb[(size_t)(b * S_ + s0 + sy) * 4096 + h * 256 + 128 + d0 + tx];
  }
  __syncthreads();
#pragma unroll
  for (int i = 0; i < 4; ++i) {
    int d = ty + i * 8;
    vtb[((size_t)bh * 128 + d0 + d) * S_ + s0 + tx] = tile[tx][d];
  }
}

// ---------------------------------------------------------------------------
// Flash attention, bf16 MFMA 16x16x32. Block 256 (4 waves), Q-tile 64
// (16 rows/wave), K-tile 64. Grid (S/64, HEADS, B).
// ---------------------------------------------------------------------------
__global__ __launch_bounds__(256) void attn_mfma(
    const unsigned short* __restrict__ qb,   // [bs][3072] bf16, rope applied
    const unsigned short* __restrict__ kvb,  // [bs][4096] bf16 (k_nope|v per head)
    const unsigned short* __restrict__ krb,  // [bs][64] bf16 roped k_rope
    const unsigned short* __restrict__ vtb,  // [(b*16+h)*128+d][s] bf16
    float* __restrict__ ao) {                // [bs][2048] fp32
  __shared__ __align__(16) unsigned short Ks[64][200];  // [key][feat] pad->2-way free
  __shared__ __align__(16) unsigned short Vt[128][72];  // [feat][key]
  __shared__ __align__(16) unsigned short Ps[4][16][72]; // per-wave P [row][key]

  const int qt = blockIdx.x, h = blockIdx.y, b = blockIdx.z;
  const int tid = threadIdx.x;
  const int lane = tid & 63, wv = tid >> 6;
  const int m = lane & 15, quad = lane >> 4;
  const int bS = b * S_;
  const float scale = 0.072168783649f;  // 1/sqrt(192)

  // Q A-fragments, loaded once: A[m=lane&15][k=quad*8+j], 6 k-chunks of 32
  bf16x8 qf[6];
  {
    const unsigned short* qptr =
        qb + (size_t)(bS + qt * 64 + wv * 16 + m) * 3072 + h * QHEAD_ + quad * 8;
#pragma unroll
    for (int c = 0; c < 6; ++c) qf[c] = *(const bf16x8*)(qptr + c * 32);
  }

  f32x4 o[8] = {};  // O [16 rows x 128 feats]: 8 n-tiles
  float m_run[4], l_run[4];
#pragma unroll
  for (int r = 0; r < 4; ++r) { m_run[r] = -3.0e38f; l_run[r] = 0.0f; }

  for (int kt = 0; kt < S_; kt += 64) {
    __syncthreads();
    // stage K: 64 keys x 192 feats (128 nope from kvb, 64 rope from krb)
#pragma unroll
    for (int it = 0; it < 6; ++it) {
      int idx = tid + it * 256;        // 0..1535
      int key = idx / 24, ch = idx % 24;
      const unsigned short* src =
          (ch < 16) ? kvb + (size_t)(bS + kt + key) * 4096 + h * 256 + ch * 8
                    : krb + (size_t)(bS + kt + key) * 64 + (ch - 16) * 8;
      *(bf16x8*)&Ks[key][ch * 8] = *(const bf16x8*)src;
    }
    // stage Vt: 128 feats x 64 keys
#pragma unroll
    for (int it = 0; it < 4; ++it) {
      int idx = tid + it * 256;        // 0..1023
      int d = idx >> 3, ch = idx & 7;
      *(bf16x8*)&Vt[d][ch * 8] =
          *(const bf16x8*)(vtb + ((size_t)(b * 16 + h) * 128 + d) * S_ + kt + ch * 8);
    }
    __syncthreads();

    // scores: S[16 x 64] = Q[16x192] K^T; 4 n-tiles x 6 k-chunks
    f32x4 sc[4] = {};
#pragma unroll
    for (int c = 0; c < 6; ++c) {
#pragma unroll
      for (int f = 0; f < 4; ++f) {
        bf16x8 kf = *(const bf16x8*)&Ks[f * 16 + m][c * 32 + quad * 8];
        sc[f] = __builtin_amdgcn_mfma_f32_16x16x32_bf16(qf[c], kf, sc[f], 0, 0, 0);
      }
    }
#pragma unroll
    for (int f = 0; f < 4; ++f) sc[f] *= scale;

    // online softmax; C-layout: row = quad*4+r, col = f*16 + m
    float p[4][4], alpha[4];
#pragma unroll
    for (int r = 0; r < 4; ++r) {
      float v = fmaxf(fmaxf(sc[0][r], sc[1][r]), fmaxf(sc[2][r], sc[3][r]));
      v = fmaxf(v, __shfl_xor(v, 1));
      v = fmaxf(v, __shfl_xor(v, 2));
      v = fmaxf(v, __shfl_xor(v, 4));
      v = fmaxf(v, __shfl_xor(v, 8));
      float mnew = fmaxf(m_run[r], v);
      float ls = 0.0f;
#pragma unroll
      for (int f = 0; f < 4; ++f) { p[f][r] = __expf(sc[f][r] - mnew); ls += p[f][r]; }
      ls += __shfl_xor(ls, 1);
      ls += __shfl_xor(ls, 2);
      ls += __shfl_xor(ls, 4);
      ls += __shfl_xor(ls, 8);
      alpha[r] = __expf(m_run[r] - mnew);
      l_run[r] = l_run[r] * alpha[r] + ls;
      m_run[r] = mnew;
    }
#pragma unroll
    for (int nt = 0; nt < 8; ++nt)
#pragma unroll
      for (int r = 0; r < 4; ++r) o[nt][r] *= alpha[r];

    // P -> LDS (C-layout scatter), then read back in A-layout (per-wave, no barrier)
#pragma unroll
    for (int f = 0; f < 4; ++f)
#pragma unroll
      for (int r = 0; r < 4; ++r)
        Ps[wv][quad * 4 + r][f * 16 + m] = f2bf(p[f][r]);

    // PV: O += P[16x64] V[64x128]
#pragma unroll
    for (int ch = 0; ch < 2; ++ch) {
      bf16x8 pf = *(const bf16x8*)&Ps[wv][m][ch * 32 + quad * 8];
#pragma unroll
      for (int nt = 0; nt < 8; ++nt) {
        bf16x8 vf = *(const bf16x8*)&Vt[nt * 16 + m][ch * 32 + quad * 8];
        o[nt] = __builtin_amdgcn_mfma_f32_16x16x32_bf16(pf, vf, o[nt], 0, 0, 0);
      }
    }
  }

#pragma unroll
  for (int r = 0; r < 4; ++r) {
    float inv = 1.0f / l_run[r];
    size_t row = (size_t)(bS + qt * 64 + wv * 16 + quad * 4 + r);
#pragma unroll
    for (int nt = 0; nt < 8; ++nt)
      ao[row * 2048 + h * VHEAD_ + nt * 16 + m] = o[nt][r] * inv;
  }
}

// ---------------------------------------------------------------------------
extern "C" void kernel_launch(void* const* d_in, const int* in_sizes, int n_in,
                              void* d_out, int out_size, void* d_ws, size_t ws_size,
                              hipStream_t stream) {
  const float* x        = (const float*)d_in[0];
  const int*   position = (const int*)d_in[1];
  const float* Wq_down  = (const float*)d_in[2];
  const float* Wq_up    = (const float*)d_in[3];
  const float* Wkv_down = (const float*)d_in[4];
  const float* Wkv_up   = (const float*)d_in[5];
  const float* Wout     = (const float*)d_in[6];
  float* out = (float*)d_out;

  char* w = (char*)d_ws;
  float*          qdown = (float*)(w);                    // 4096x1024 f32   16.8MB
  unsigned short* qb    = (unsigned short*)(w + 16777216);  // 4096x3072 bf16 25.2MB
  float*          ckv   = (float*)(w + 41943040);           // 4096x576 f32    9.4MB
  unsigned short* kvb   = (unsigned short*)(w + 51380224);  // 4096x4096 bf16 33.6MB
  unsigned short* vtb   = (unsigned short*)(w + 84934656);  // 32x128x2048 bf16 16.8MB
  unsigned short* krb   = (unsigned short*)(w + 101711872); // 4096x64 bf16    0.5MB
  float*          ao    = (float*)(w + 102236160);          // 4096x2048 f32  33.6MB

  dim3 blk(16, 16);

  // qdown = x @ Wq_down (f32)
  gemm_f32_t<float><<<dim3(1024 / 64, 4096 / 64), blk, 0, stream>>>(
      x, HIDDEN_, Wq_down, QLORA_, qdown, QLORA_, HIDDEN_);
  // qb = qdown @ Wq_up (bf16 out)
  gemm_f32_t<unsigned short><<<dim3(3072 / 64, 4096 / 64), blk, 0, stream>>>(
      qdown, QLORA_, Wq_up, 3072, qb, 3072, QLORA_);
  // ckv = x @ Wkv_down (f32)
  gemm_f32_t<float><<<dim3(576 / 64, 4096 / 64), blk, 0, stream>>>(
      x, HIDDEN_, Wkv_down, 576, ckv, 576, HIDDEN_);
  // rope: qb in-place (bf16), ckv rope cols -> krb (bf16)
  {
    int total = B_ * S_ * 17 * 32;
    rope_kernel<<<(total + 255) / 256, 256, 0, stream>>>(qb, ckv, krb, position);
  }
  // kvb = ckv[:, :512] @ Wkv_up (bf16 out)
  gemm_f32_t<unsigned short><<<dim3(4096 / 64, 4096 / 64), blk, 0, stream>>>(
      ckv, 576, Wkv_up, 4096, kvb, 4096, KVLORA_);
  // vtb = transpose(V) per head
  pack_vt<<<dim3(S_ / 32, 128 / 32, B_ * HEADS_), dim3(32, 8), 0, stream>>>(kvb, vtb);
  // attention
  attn_mfma<<<dim3(S_ / 64, HEADS_, B_), 256, 0, stream>>>(qb, kvb, krb, vtb, ao);
  // out = ao @ Wout (f32)
  gemm_f32_t<float><<<dim3(2048 / 64, 4096 / 64), blk, 0, stream>>>(
      ao, HIDDEN_, Wout, HIDDEN_, out, HIDDEN_, HIDDEN_);
}

// Round 3
// 580.039 us; speedup vs baseline: 6.8814x; 3.0322x over previous
//
#include <hip/hip_runtime.h>
#include <math.h>

#define B_      2
#define S_      2048
#define HIDDEN_ 2048
#define HEADS_  16
#define QLORA_  1024
#define KVLORA_ 512
#define NOPE_   128
#define ROPE_   64
#define QHEAD_  192
#define VHEAD_  128

typedef __attribute__((ext_vector_type(8))) short bf16x8;
typedef __attribute__((ext_vector_type(4))) float f32x4;

static __device__ __forceinline__ unsigned short f2bf(float f) {
  unsigned u = __builtin_bit_cast(unsigned, f);
  u += 0x7fffu + ((u >> 16) & 1u);  // RTNE
  return (unsigned short)(u >> 16);
}
static __device__ __forceinline__ float b2f(unsigned short s) {
  unsigned u = ((unsigned)s) << 16;
  return __builtin_bit_cast(float, u);
}

// ---------------------------------------------------------------------------
// bf16 MFMA GEMM (m97 "gemm_bt" structure): C[M,N] = A[M,K] @ Bt[N,K]^T
// Tile 128x128, BK=32, block 256 (4 waves, 2x2 of 64x64), 4x4 MFMA acc/wave.
// global_load_lds width=16 staging; XOR k-chunk swizzle -> 2-way LDS reads.
// TC = unsigned short (bf16 out) or float.
// ---------------------------------------------------------------------------
template <typename TC>
__global__ __launch_bounds__(256) void gemm_bt(
    const unsigned short* __restrict__ A, int lda,   // [M][K] bf16
    const unsigned short* __restrict__ Bt, int ldb,  // [N][K] bf16
    TC* __restrict__ C, int ldc, int K) {
  __shared__ __align__(16) unsigned short As[128][32];  // 8 KB
  __shared__ __align__(16) unsigned short Bs[128][32];  // 8 KB

  const int tid = threadIdx.x;
  const int lane = tid & 63, wv = tid >> 6;
  const int m = lane & 15, quad = lane >> 4;
  const int wm = wv >> 1, wn = wv & 1;
  const int bm = blockIdx.y * 128, bn = blockIdx.x * 128;

  // staging: inst t covers LDS rows t*16..t*16+15; HW writes lane -> base+lane*16B
  // lane: row = t*16 + (lane>>2), LDS slot = lane&3, fetched global chunk:
  const int srow = lane >> 2;
  const int gchunk = (lane & 3) ^ ((lane >> 3) & 3);
  // compute-side: global k-chunk `quad` of row r lives at slot quad^((r>>1)&3);
  // (r>>1)&3 == ((m>>1)&3) for all our tile rows -> per-lane constant.
  const int koff = (quad ^ ((m >> 1) & 3)) * 8;

  f32x4 acc[4][4] = {};

  const unsigned short* Ab = A + (size_t)bm * lda;
  const unsigned short* Bb = Bt + (size_t)bn * ldb;

  for (int k0 = 0; k0 < K; k0 += 32) {
    __syncthreads();  // previous iteration's readers done
#pragma unroll
    for (int j = 0; j < 2; ++j) {
      const int t = wv * 2 + j;
      const int r = t * 16 + srow;
      __builtin_amdgcn_global_load_lds(
          (const __attribute__((address_space(1))) unsigned int*)(Ab + (size_t)r * lda + k0 + gchunk * 8),
          (__attribute__((address_space(3))) unsigned int*)(&As[0][0] + t * 512),
          16, 0, 0);
      __builtin_amdgcn_global_load_lds(
          (const __attribute__((address_space(1))) unsigned int*)(Bb + (size_t)r * ldb + k0 + gchunk * 8),
          (__attribute__((address_space(3))) unsigned int*)(&Bs[0][0] + t * 512),
          16, 0, 0);
    }
    __syncthreads();  // drains vmcnt -> LDS tiles complete

    bf16x8 af[4], bfr[4];
#pragma unroll
    for (int mt = 0; mt < 4; ++mt)
      af[mt] = *(const bf16x8*)&As[wm * 64 + mt * 16 + m][koff];
#pragma unroll
    for (int nt = 0; nt < 4; ++nt)
      bfr[nt] = *(const bf16x8*)&Bs[wn * 64 + nt * 16 + m][koff];
#pragma unroll
    for (int mt = 0; mt < 4; ++mt)
#pragma unroll
      for (int nt = 0; nt < 4; ++nt)
        acc[mt][nt] = __builtin_amdgcn_mfma_f32_16x16x32_bf16(af[mt], bfr[nt], acc[mt][nt], 0, 0, 0);
  }

  // C-layout: row = quad*4 + reg, col = m (per 16x16 tile)
#pragma unroll
  for (int mt = 0; mt < 4; ++mt) {
#pragma unroll
    for (int reg = 0; reg < 4; ++reg) {
      const size_t row = (size_t)bm + wm * 64 + mt * 16 + quad * 4 + reg;
#pragma unroll
      for (int nt = 0; nt < 4; ++nt) {
        const size_t col = (size_t)bn + wn * 64 + nt * 16 + m;
        float v = acc[mt][nt][reg];
        if constexpr (sizeof(TC) == 4) {
          ((float*)C)[row * ldc + col] = v;
        } else {
          ((unsigned short*)C)[row * ldc + col] = f2bf(v);
        }
      }
    }
  }
}

// ---------------------------------------------------------------------------
// Weight transpose+cast: W fp32 [K][N] -> Wt bf16 [Npad][K] (zero-pad n>=N).
// Grid (K/32, Npad/32), block (32,8).
// ---------------------------------------------------------------------------
__global__ __launch_bounds__(256) void transpose_cast(
    const float* __restrict__ W, int K, int N,
    unsigned short* __restrict__ Wt) {
  __shared__ unsigned short t[32][33];
  const int k0 = blockIdx.x * 32, n0 = blockIdx.y * 32;
  const int tx = threadIdx.x, ty = threadIdx.y;
#pragma unroll
  for (int i = 0; i < 4; ++i) {
    int k = k0 + ty + i * 8, n = n0 + tx;
    float v = (n < N) ? W[(size_t)k * N + n] : 0.0f;
    t[ty + i * 8][tx] = f2bf(v);
  }
  __syncthreads();
#pragma unroll
  for (int i = 0; i < 4; ++i) {
    int n = ty + i * 8;
    Wt[(size_t)(n0 + n) * K + k0 + tx] = t[tx][n];
  }
}

// ---------------------------------------------------------------------------
// x fp32 -> bf16 (vectorized)
// ---------------------------------------------------------------------------
__global__ void cast_bf16(const float* __restrict__ src,
                          unsigned short* __restrict__ dst, int n4) {
  int i = blockIdx.x * blockDim.x + threadIdx.x;
  if (i >= n4) return;
  float4 v = ((const float4*)src)[i];
  ushort4 o;
  o.x = f2bf(v.x); o.y = f2bf(v.y); o.z = f2bf(v.z); o.w = f2bf(v.w);
  ((ushort4*)dst)[i] = o;
}

// ---------------------------------------------------------------------------
// RoPE: qb bf16 in-place (cols h*192+128..191); k_rope from ckvb bf16 [bs][640]
// cols 512..575 -> krb bf16 [bs][64].
// ---------------------------------------------------------------------------
__global__ void rope_kernel(unsigned short* __restrict__ qb,
                            const unsigned short* __restrict__ ckvb,
                            unsigned short* __restrict__ krb,
                            const int* __restrict__ position) {
  int idx = blockIdx.x * blockDim.x + threadIdx.x;
  const int total = B_ * S_ * 17 * 32;
  if (idx >= total) return;
  int i = idx & 31;
  int u = idx >> 5;
  int h = u % 17;
  int bs = u / 17;
  int s = bs % S_;
  float pos = (float)position[s];
  float inv_freq = powf(10000.0f, -(float)i / 32.0f);
  float ang = pos * inv_freq;
  float c = cosf(ang), sn = sinf(ang);
  if (h < 16) {
    unsigned short* t = qb + (size_t)bs * 3072 + h * QHEAD_ + NOPE_;
    float t1 = b2f(t[i]), t2 = b2f(t[i + 32]);
    t[i]      = f2bf(t1 * c - t2 * sn);
    t[i + 32] = f2bf(t2 * c + t1 * sn);
  } else {
    const unsigned short* t = ckvb + (size_t)bs * 640 + 512;
    float t1 = b2f(t[i]), t2 = b2f(t[i + 32]);
    krb[(size_t)bs * 64 + i]      = f2bf(t1 * c - t2 * sn);
    krb[(size_t)bs * 64 + i + 32] = f2bf(t2 * c + t1 * sn);
  }
}

// ---------------------------------------------------------------------------
// V transpose: kvb bf16 [bs][h*256+128+d] -> vtb bf16 [(b*16+h)*128+d][s]
// ---------------------------------------------------------------------------
__global__ __launch_bounds__(256) void pack_vt(const unsigned short* __restrict__ kvb,
                                               unsigned short* __restrict__ vtb) {
  __shared__ unsigned short tile[32][33];
  int s0 = blockIdx.x * 32, d0 = blockIdx.y * 32, bh = blockIdx.z;
  int b = bh >> 4, h = bh & 15;
  int tx = threadIdx.x, ty = threadIdx.y;  // block (32,8)
#pragma unroll
  for (int i = 0; i < 4; ++i) {
    int sy = ty + i * 8;
    tile[sy][tx] = kvb[(size_t)(b * S_ + s0 + sy) * 4096 + h * 256 + 128 + d0 + tx];
  }
  __syncthreads();
#pragma unroll
  for (int i = 0; i < 4; ++i) {
    int d = ty + i * 8;
    vtb[((size_t)bh * 128 + d0 + d) * S_ + s0 + tx] = tile[tx][d];
  }
}

// ---------------------------------------------------------------------------
// Flash attention, bf16 MFMA 16x16x32 (verified R2). Output now bf16 (aob).
// ---------------------------------------------------------------------------
__global__ __launch_bounds__(256) void attn_mfma(
    const unsigned short* __restrict__ qb,   // [bs][3072] bf16, rope applied
    const unsigned short* __restrict__ kvb,  // [bs][4096] bf16 (k_nope|v per head)
    const unsigned short* __restrict__ krb,  // [bs][64] bf16 roped k_rope
    const unsigned short* __restrict__ vtb,  // [(b*16+h)*128+d][s] bf16
    unsigned short* __restrict__ aob) {      // [bs][2048] bf16
  __shared__ __align__(16) unsigned short Ks[64][200];
  __shared__ __align__(16) unsigned short Vt[128][72];
  __shared__ __align__(16) unsigned short Ps[4][16][72];

  const int qt = blockIdx.x, h = blockIdx.y, b = blockIdx.z;
  const int tid = threadIdx.x;
  const int lane = tid & 63, wv = tid >> 6;
  const int m = lane & 15, quad = lane >> 4;
  const int bS = b * S_;
  const float scale = 0.072168783649f;  // 1/sqrt(192)

  bf16x8 qf[6];
  {
    const unsigned short* qptr =
        qb + (size_t)(bS + qt * 64 + wv * 16 + m) * 3072 + h * QHEAD_ + quad * 8;
#pragma unroll
    for (int c = 0; c < 6; ++c) qf[c] = *(const bf16x8*)(qptr + c * 32);
  }

  f32x4 o[8] = {};
  float m_run[4], l_run[4];
#pragma unroll
  for (int r = 0; r < 4; ++r) { m_run[r] = -3.0e38f; l_run[r] = 0.0f; }

  for (int kt = 0; kt < S_; kt += 64) {
    __syncthreads();
#pragma unroll
    for (int it = 0; it < 6; ++it) {
      int idx = tid + it * 256;
      int key = idx / 24, ch = idx % 24;
      const unsigned short* src =
          (ch < 16) ? kvb + (size_t)(bS + kt + key) * 4096 + h * 256 + ch * 8
                    : krb + (size_t)(bS + kt + key) * 64 + (ch - 16) * 8;
      *(bf16x8*)&Ks[key][ch * 8] = *(const bf16x8*)src;
    }
#pragma unroll
    for (int it = 0; it < 4; ++it) {
      int idx = tid + it * 256;
      int d = idx >> 3, ch = idx & 7;
      *(bf16x8*)&Vt[d][ch * 8] =
          *(const bf16x8*)(vtb + ((size_t)(b * 16 + h) * 128 + d) * S_ + kt + ch * 8);
    }
    __syncthreads();

    f32x4 sc[4] = {};
#pragma unroll
    for (int c = 0; c < 6; ++c) {
#pragma unroll
      for (int f = 0; f < 4; ++f) {
        bf16x8 kf = *(const bf16x8*)&Ks[f * 16 + m][c * 32 + quad * 8];
        sc[f] = __builtin_amdgcn_mfma_f32_16x16x32_bf16(qf[c], kf, sc[f], 0, 0, 0);
      }
    }
#pragma unroll
    for (int f = 0; f < 4; ++f) sc[f] *= scale;

    float p[4][4], alpha[4];
#pragma unroll
    for (int r = 0; r < 4; ++r) {
      float v = fmaxf(fmaxf(sc[0][r], sc[1][r]), fmaxf(sc[2][r], sc[3][r]));
      v = fmaxf(v, __shfl_xor(v, 1));
      v = fmaxf(v, __shfl_xor(v, 2));
      v = fmaxf(v, __shfl_xor(v, 4));
      v = fmaxf(v, __shfl_xor(v, 8));
      float mnew = fmaxf(m_run[r], v);
      float ls = 0.0f;
#pragma unroll
      for (int f = 0; f < 4; ++f) { p[f][r] = __expf(sc[f][r] - mnew); ls += p[f][r]; }
      ls += __shfl_xor(ls, 1);
      ls += __shfl_xor(ls, 2);
      ls += __shfl_xor(ls, 4);
      ls += __shfl_xor(ls, 8);
      alpha[r] = __expf(m_run[r] - mnew);
      l_run[r] = l_run[r] * alpha[r] + ls;
      m_run[r] = mnew;
    }
#pragma unroll
    for (int nt = 0; nt < 8; ++nt)
#pragma unroll
      for (int r = 0; r < 4; ++r) o[nt][r] *= alpha[r];

#pragma unroll
    for (int f = 0; f < 4; ++f)
#pragma unroll
      for (int r = 0; r < 4; ++r)
        Ps[wv][quad * 4 + r][f * 16 + m] = f2bf(p[f][r]);

#pragma unroll
    for (int ch = 0; ch < 2; ++ch) {
      bf16x8 pf = *(const bf16x8*)&Ps[wv][m][ch * 32 + quad * 8];
#pragma unroll
      for (int nt = 0; nt < 8; ++nt) {
        bf16x8 vf = *(const bf16x8*)&Vt[nt * 16 + m][ch * 32 + quad * 8];
        o[nt] = __builtin_amdgcn_mfma_f32_16x16x32_bf16(pf, vf, o[nt], 0, 0, 0);
      }
    }
  }

#pragma unroll
  for (int r = 0; r < 4; ++r) {
    float inv = 1.0f / l_run[r];
    size_t row = (size_t)(bS + qt * 64 + wv * 16 + quad * 4 + r);
#pragma unroll
    for (int nt = 0; nt < 8; ++nt)
      aob[row * 2048 + h * VHEAD_ + nt * 16 + m] = f2bf(o[nt][r] * inv);
  }
}

// ---------------------------------------------------------------------------
extern "C" void kernel_launch(void* const* d_in, const int* in_sizes, int n_in,
                              void* d_out, int out_size, void* d_ws, size_t ws_size,
                              hipStream_t stream) {
  const float* x        = (const float*)d_in[0];
  const int*   position = (const int*)d_in[1];
  const float* Wq_down  = (const float*)d_in[2];  // [2048,1024]
  const float* Wq_up    = (const float*)d_in[3];  // [1024,3072]
  const float* Wkv_down = (const float*)d_in[4];  // [2048,576]
  const float* Wkv_up   = (const float*)d_in[5];  // [512,4096]
  const float* Wout     = (const float*)d_in[6];  // [2048,2048]
  float* out = (float*)d_out;

  char* w = (char*)d_ws;
  size_t off = 0;
  auto alloc = [&](size_t bytes) { char* p = w + off; off += (bytes + 255) & ~size_t(255); return p; };
  unsigned short* xb     = (unsigned short*)alloc(4096ull * 2048 * 2);  // 16.8 MB
  unsigned short* qdownb = (unsigned short*)alloc(4096ull * 1024 * 2);  //  8.4 MB
  unsigned short* qb     = (unsigned short*)alloc(4096ull * 3072 * 2);  // 25.2 MB
  unsigned short* ckvb   = (unsigned short*)alloc(4096ull * 640 * 2);   //  5.2 MB
  unsigned short* kvb    = (unsigned short*)alloc(4096ull * 4096 * 2);  // 33.6 MB
  unsigned short* vtb    = (unsigned short*)alloc(32ull * 128 * 2048 * 2); // 16.8 MB
  unsigned short* krb    = (unsigned short*)alloc(4096ull * 64 * 2);    //  0.5 MB
  unsigned short* aob    = (unsigned short*)alloc(4096ull * 2048 * 2);  // 16.8 MB
  unsigned short* Wqd_t  = (unsigned short*)alloc(1024ull * 2048 * 2);  //  4.2 MB
  unsigned short* Wqu_t  = (unsigned short*)alloc(3072ull * 1024 * 2);  //  6.3 MB
  unsigned short* Wkvd_t = (unsigned short*)alloc(640ull * 2048 * 2);   //  2.6 MB
  unsigned short* Wkvu_t = (unsigned short*)alloc(4096ull * 512 * 2);   //  4.2 MB
  unsigned short* Wout_t = (unsigned short*)alloc(2048ull * 2048 * 2);  //  8.4 MB

  dim3 tblk(32, 8);

  // casts / transposes (one-time per launch)
  cast_bf16<<<(4096 * 2048 / 4 + 255) / 256, 256, 0, stream>>>(x, xb, 4096 * 2048 / 4);
  transpose_cast<<<dim3(2048 / 32, 1024 / 32), tblk, 0, stream>>>(Wq_down, 2048, 1024, Wqd_t);
  transpose_cast<<<dim3(1024 / 32, 3072 / 32), tblk, 0, stream>>>(Wq_up, 1024, 3072, Wqu_t);
  transpose_cast<<<dim3(2048 / 32, 640 / 32), tblk, 0, stream>>>(Wkv_down, 2048, 576, Wkvd_t);
  transpose_cast<<<dim3(512 / 32, 4096 / 32), tblk, 0, stream>>>(Wkv_up, 512, 4096, Wkvu_t);
  transpose_cast<<<dim3(2048 / 32, 2048 / 32), tblk, 0, stream>>>(Wout, 2048, 2048, Wout_t);

  // qdownb = xb @ Wq_down (M=4096, N=1024, K=2048)
  gemm_bt<unsigned short><<<dim3(1024 / 128, 32), 256, 0, stream>>>(
      xb, 2048, Wqd_t, 2048, qdownb, 1024, 2048);
  // qb = qdownb @ Wq_up (N=3072, K=1024)
  gemm_bt<unsigned short><<<dim3(3072 / 128, 32), 256, 0, stream>>>(
      qdownb, 1024, Wqu_t, 1024, qb, 3072, 1024);
  // ckvb = xb @ Wkv_down (N=640 padded, K=2048)
  gemm_bt<unsigned short><<<dim3(640 / 128, 32), 256, 0, stream>>>(
      xb, 2048, Wkvd_t, 2048, ckvb, 640, 2048);
  // rope
  {
    int total = B_ * S_ * 17 * 32;
    rope_kernel<<<(total + 255) / 256, 256, 0, stream>>>(qb, ckvb, krb, position);
  }
  // kvb = ckvb[:, :512] @ Wkv_up (N=4096, K=512; lda=640 skips pad+rope cols)
  gemm_bt<unsigned short><<<dim3(4096 / 128, 32), 256, 0, stream>>>(
      ckvb, 640, Wkvu_t, 512, kvb, 4096, 512);
  // vtb = transpose(V) per head
  pack_vt<<<dim3(S_ / 32, 128 / 32, B_ * HEADS_), tblk, 0, stream>>>(kvb, vtb);
  // attention -> aob (bf16)
  attn_mfma<<<dim3(S_ / 64, HEADS_, B_), 256, 0, stream>>>(qb, kvb, krb, vtb, aob);
  // out = aob @ Wout (N=2048, K=2048, fp32 out)
  gemm_bt<float><<<dim3(2048 / 128, 32), 256, 0, stream>>>(
      aob, 2048, Wout_t, 2048, out, 2048, 2048);
}